// Round 2
// baseline (276.655 us; speedup 1.0000x reference)
//
#include <hip/hip_runtime.h>
#include <hip/hip_cooperative_groups.h>

namespace cg = cooperative_groups;

// Problem constants (from reference): B=8, L=2048, H=1024, C=64
#define PB 8
#define PL 2048
#define PH 1024
#define PC 64
#define NROWS (PB * PL)          // 16384
#define NSPANS (PB * PC)         // 512

#define GRID_BLOCKS 1024         // 4 blocks/CU, 16 waves/CU -> co-resident
#define BLOCK_THREADS 256
#define NWAVES (GRID_BLOCKS * (BLOCK_THREADS / 64))  // 4096
#define ROWS_PER_WAVE (NROWS / NWAVES)               // 4

// Fused: phase 1 row-dot (s[b,l] = <feature[b,l,:], w>), grid sync,
// phase 2 span mean-pool + bias.
__global__ __launch_bounds__(BLOCK_THREADS) void fused_kernel(
    const float* __restrict__ feature,   // [B*L, H]
    const float* __restrict__ w,         // [H]
    const float* __restrict__ bias,      // [1]
    const int* __restrict__ pos,         // [B*C, 2]
    float* __restrict__ out,             // [B*C]
    float* __restrict__ s)               // [B*L] scratch
{
    cg::grid_group grid = cg::this_grid();

    const int wid  = blockIdx.x * (BLOCK_THREADS / 64) + (threadIdx.x >> 6);
    const int lane = threadIdx.x & 63;

    // ---- Phase 1: s[row] = dot(feature[row,:], w) ----
    // Preload this lane's w fragment once (16 floats, reused for 4 rows).
    float4 wf[PH / 256];
#pragma unroll
    for (int j = 0; j < PH / 256; ++j)
        wf[j] = *reinterpret_cast<const float4*>(w + j * 256 + lane * 4);

#pragma unroll
    for (int r = 0; r < ROWS_PER_WAVE; ++r) {
        const int row = wid + r * NWAVES;
        const float* rp = feature + (size_t)row * PH;
        float acc = 0.0f;
#pragma unroll
        for (int j = 0; j < PH / 256; ++j) {
            float4 f = *reinterpret_cast<const float4*>(rp + j * 256 + lane * 4);
            acc += f.x * wf[j].x + f.y * wf[j].y + f.z * wf[j].z + f.w * wf[j].w;
        }
#pragma unroll
        for (int off = 32; off > 0; off >>= 1)
            acc += __shfl_down(acc, off, 64);
        if (lane == 0) s[row] = acc;
    }

    // ---- Grid-wide sync (device-scope fence + barrier) ----
    __threadfence();
    grid.sync();

    // ---- Phase 2: one wave per span ----
    if (wid < NSPANS) {
        const int span = wid;
        const int b    = span >> 6;            // span / PC
        const int src  = pos[span * 2 + 0];
        const int end  = pos[span * 2 + 1];
        const float* sb = s + b * PL;

        float acc = 0.0f;
        for (int l = src + lane; l <= end; l += 64)
            acc += sb[l];
#pragma unroll
        for (int off = 32; off > 0; off >>= 1)
            acc += __shfl_down(acc, off, 64);

        if (lane == 0) {
            const float cnt = (float)(end - src + 1);   // src<=end, cnt>=1
            out[span] = acc / cnt + bias[0];
        }
    }
}

extern "C" void kernel_launch(void* const* d_in, const int* in_sizes, int n_in,
                              void* d_out, int out_size, void* d_ws, size_t ws_size,
                              hipStream_t stream) {
    const float* feature = (const float*)d_in[0];   // [B, L, H] fp32
    const float* fc_w    = (const float*)d_in[1];   // [1, H]
    const float* fc_b    = (const float*)d_in[2];   // [1]
    const int*   pos     = (const int*)d_in[3];     // [B, C, 2] int32
    float*       out     = (float*)d_out;           // [B*C, 1] fp32
    float*       s       = (float*)d_ws;            // B*L floats = 64 KB scratch

    void* args[] = { (void*)&feature, (void*)&fc_w, (void*)&fc_b,
                     (void*)&pos, (void*)&out, (void*)&s };
    hipLaunchCooperativeKernel((const void*)fused_kernel,
                               dim3(GRID_BLOCKS), dim3(BLOCK_THREADS),
                               args, 0, stream);
}

// Round 3
// 101.914 us; speedup vs baseline: 2.7146x; 2.7146x over previous
//
#include <hip/hip_runtime.h>

// Problem constants (from reference): B=8, L=2048, H=1024, C=64
#define PB 8
#define PL 2048
#define PH 1024
#define PC 64
#define NROWS (PB * PL)          // 16384
#define NSPANS (PB * PC)         // 512

// Kernel 1: s[row] = dot(feature[row,:], w) for row in [0, B*L)
// 1024 blocks x 256 threads = 4096 waves; 4 consecutive rows per wave
// (16 KB contiguous feature per wave). w fragment (16 floats/lane) is
// preloaded ONCE per wave into VGPRs and reused across the 4 rows —
// R1 re-fetched w per row, doubling VMEM instruction count.
#define K1_BLOCKS 1024
#define ROWS_PER_WAVE 4

__global__ __launch_bounds__(256) void row_dot_kernel(
    const float* __restrict__ feature,   // [B*L, H]
    const float* __restrict__ w,         // [H]
    float* __restrict__ s)               // [B*L]
{
    const int wid  = blockIdx.x * 4 + (threadIdx.x >> 6);   // 0..4095
    const int lane = threadIdx.x & 63;

    // Preload w fragment: lane covers H-positions {j*256 + lane*4 .. +3}
    float4 wf[PH / 256];
#pragma unroll
    for (int j = 0; j < PH / 256; ++j)
        wf[j] = *reinterpret_cast<const float4*>(w + j * 256 + lane * 4);

    const float* base = feature + (size_t)wid * ROWS_PER_WAVE * PH;

#pragma unroll
    for (int r = 0; r < ROWS_PER_WAVE; ++r) {
        const float* rp = base + r * PH;
        float acc = 0.0f;
#pragma unroll
        for (int j = 0; j < PH / 256; ++j) {
            float4 f = *reinterpret_cast<const float4*>(rp + j * 256 + lane * 4);
            acc += f.x * wf[j].x + f.y * wf[j].y + f.z * wf[j].z + f.w * wf[j].w;
        }
#pragma unroll
        for (int off = 32; off > 0; off >>= 1)
            acc += __shfl_down(acc, off, 64);
        if (lane == 0) s[wid * ROWS_PER_WAVE + r] = acc;
    }
}

// Kernel 2: per (b,c) span, mean of s[b, src..end] + bias. One wave per span.
__global__ __launch_bounds__(256) void span_pool_kernel(
    const float* __restrict__ s,         // [B, L]
    const int* __restrict__ pos,         // [B*C, 2] (src, end) inclusive
    const float* __restrict__ bias,      // [1]
    float* __restrict__ out)             // [B*C]
{
    const int gtid = blockIdx.x * 256 + threadIdx.x;
    const int span = gtid >> 6;          // 0..511
    const int lane = threadIdx.x & 63;

    const int b   = span >> 6;           // span / PC
    const int src = pos[span * 2 + 0];
    const int end = pos[span * 2 + 1];

    const float* sb = s + b * PL;
    float acc = 0.0f;
    for (int l = src + lane; l <= end; l += 64)
        acc += sb[l];

#pragma unroll
    for (int off = 32; off > 0; off >>= 1)
        acc += __shfl_down(acc, off, 64);

    if (lane == 0) {
        const float cnt = (float)(end - src + 1);   // src<=end guaranteed
        out[span] = acc / cnt + bias[0];
    }
}

extern "C" void kernel_launch(void* const* d_in, const int* in_sizes, int n_in,
                              void* d_out, int out_size, void* d_ws, size_t ws_size,
                              hipStream_t stream) {
    const float* feature = (const float*)d_in[0];   // [B, L, H] fp32
    const float* fc_w    = (const float*)d_in[1];   // [1, H]
    const float* fc_b    = (const float*)d_in[2];   // [1]
    const int*   pos     = (const int*)d_in[3];     // [B, C, 2] int32
    float*       out     = (float*)d_out;           // [B*C, 1] fp32
    float*       s       = (float*)d_ws;            // B*L floats = 64 KB scratch

    row_dot_kernel<<<K1_BLOCKS, 256, 0, stream>>>(feature, fc_w, s);
    span_pool_kernel<<<(NSPANS * 64) / 256, 256, 0, stream>>>(s, pos, fc_b, out);
}